// Round 8
// baseline (654.401 us; speedup 1.0000x reference)
//
#include <hip/hip_runtime.h>
#include <hip/hip_bf16.h>

// Problem: B=64, L=1024, ENC=1024, DEC=1024, ATT=1024
// M = B*L = 65536, K = ENC = 1024, N = ATT = 1024
//
// Pipeline (fast path, needs ~135 MB ws):
//   ws: [featb bf16 128MB][W1T bf16 2MB][proj_h fp32 256KB][part fp32 4MB]
//   1. convert features fp32 -> bf16 (featb)
//   2. transpose W1 (fp32 [K][N]) -> W1T (bf16 [N][K])
//   3. proj_h = hidden@W2 + W2_b + W1_b   (combined bias)
//   4. GEMM proj_f = featb@W1T: 256x128 tile, 512 thr / 8 waves (2x MFMA per
//      barrier vs 128x128/4-wave), bf16 MFMA, global_load_lds staging,
//      XOR-swizzled LDS, cheap-tanh epilogue, XCD-aware block remap.
//        part[nt*2 + colhalf][m] = sum_{a in 64-col chunk} tanh(pf+ph)*V_w
//   5. softmax over L (summing 16 partials/row) -> alpha (d_out[0:65536])
//   6. context[b][e] = sum_l alpha*featb (bf16 feat)

typedef __bf16 bf16x8 __attribute__((ext_vector_type(8)));
typedef float floatx4 __attribute__((ext_vector_type(4)));
typedef unsigned short ushort_t;
typedef unsigned long long u64;

__device__ __forceinline__ ushort_t f2b(float x) {
    union { float f; unsigned u; } v; v.f = x;
    unsigned r = (v.u + 0x7fffu + ((v.u >> 16) & 1u)) >> 16;  // RNE
    return (ushort_t)r;
}

__device__ __forceinline__ float b2f(ushort_t u) {
    union { unsigned u; float f; } v; v.u = (unsigned)u << 16; return v.f;
}

__device__ __forceinline__ u64 pack4(float4 f) {
    return (u64)f2b(f.x) | ((u64)f2b(f.y) << 16) |
           ((u64)f2b(f.z) << 32) | ((u64)f2b(f.w) << 48);
}

__device__ __forceinline__ void gload_lds16(const void* g, void* l) {
    __builtin_amdgcn_global_load_lds(
        (const __attribute__((address_space(1))) void*)g,
        (__attribute__((address_space(3))) void*)l, 16, 0, 0);
}

// tanh via v_exp_f32 + v_rcp_f32 (fallback kernel only)
__device__ __forceinline__ float fast_tanh(float x) {
    const float ax = fabsf(x);
    const float t  = __expf(-2.0f * ax);
    const float r  = (1.0f - t) * __builtin_amdgcn_rcpf(1.0f + t);
    return copysignf(r, x);
}

// ---------------- features fp32 -> bf16 -------------------------------------
__global__ __launch_bounds__(256) void convert_feat_kernel(
    const float* __restrict__ feat, ushort_t* __restrict__ featb) {
    const size_t idx = ((size_t)blockIdx.x * 256 + threadIdx.x) * 8;
    const float4 f0 = *(const float4*)(feat + idx);
    const float4 f1 = *(const float4*)(feat + idx + 4);
    *(u64*)(featb + idx)     = pack4(f0);
    *(u64*)(featb + idx + 4) = pack4(f1);
}

// ---------------- W1 transpose + bf16 convert: [K][N] fp32 -> [N][K] bf16 ---
__global__ __launch_bounds__(256) void transpose_w1_kernel(
    const float* __restrict__ w1, ushort_t* __restrict__ w1t) {
    __shared__ ushort_t tile[64][65];
    const int k0 = blockIdx.x * 64, n0 = blockIdx.y * 64;
    const int tr = threadIdx.x >> 6;   // 0..3
    const int tc = threadIdx.x & 63;   // 0..63
#pragma unroll
    for (int i = 0; i < 16; i++) {
        int r = i * 4 + tr;
        tile[tc][r] = f2b(w1[(size_t)(k0 + r) * 1024 + n0 + tc]);
    }
    __syncthreads();
#pragma unroll
    for (int i = 0; i < 16; i++) {
        int r = i * 4 + tr;
        w1t[(size_t)(n0 + r) * 1024 + k0 + tc] = tile[r][tc];
    }
}

// ---------------- proj_h = hidden @ W2 + W2_b + W1_b ------------------------
__global__ __launch_bounds__(256) void projh_kernel(
    const float* __restrict__ hidden, const float* __restrict__ w2,
    const float* __restrict__ w2b, const float* __restrict__ w1b,
    float* __restrict__ ph) {
    const int b  = blockIdx.y;
    const int al = threadIdx.x & 63;
    const int eg = threadIdx.x >> 6;            // 0..3
    const int a  = blockIdx.x * 64 + al;
    const float* h = hidden + b * 1024;
    float sum = 0.f;
    const int e0 = eg * 256;
#pragma unroll 8
    for (int e = e0; e < e0 + 256; e++)
        sum += h[e] * w2[(size_t)e * 1024 + a];
    __shared__ float red[256];
    red[threadIdx.x] = sum;
    __syncthreads();
    if (threadIdx.x < 64)
        ph[b * 1024 + a] = w2b[a] + w1b[a] + red[al] + red[al + 64] +
                           red[al + 128] + red[al + 192];
}

// ---------------- main GEMM: 256x128 tile, 512 threads, 8 waves -------------
// Wave grid 4m x 2n, each wave 64x64 (4x4 MFMA 16x16x32). BK=64.
// LDS rows are 8 x 16B blocks; block b of row r holds global block b^(r&7).
#define LOG2E2 2.885390082f   // 2/ln(2): e^{2x} = 2^{x*LOG2E2}

__global__ __launch_bounds__(512, 2) void gemm_scores_bf16_kernel(
    const ushort_t* __restrict__ featb,  // [M][1024] bf16
    const ushort_t* __restrict__ w1t,    // [N][1024] bf16
    const float* __restrict__ ph,        // [B][1024] combined bias
    const float* __restrict__ vw,        // [1024]
    float* __restrict__ part) {          // [16][M] fp32 partial scores
    __shared__ ushort_t As[256 * 64];    // 32 KB
    __shared__ ushort_t Bs[128 * 64];    // 16 KB
    __shared__ float cbias[128];
    __shared__ float vvw[128];

    const int tid = threadIdx.x;
    const int lid = blockIdx.y * 8 + blockIdx.x;     // HW linear id, x fastest
    const int c   = lid & 7;
    const int rr  = lid >> 3;
    const int mt  = (rr >> 3) * 8 + c;               // m-tile 0..255
    const int nt  = rr & 7;                          // n-tile 0..7
    const int n0 = nt * 128;
    const int m0 = mt * 256;
    const int b  = m0 >> 10;             // BM=256 divides L=1024 -> one b

    if (tid < 128) {
        cbias[tid] = ph[(b << 10) + n0 + tid];
        vvw[tid]   = vw[n0 + tid];
    }

    const int wave = tid >> 6;           // 0..7
    const int lane = tid & 63;
    const int wr = (wave >> 1) * 64;     // 0,64,128,192
    const int wc = (wave & 1) * 64;      // 0,64
    const int q  = lane >> 4;
    const int l15 = lane & 15;

    floatx4 acc[4][4] = {};

    // staging: lane i -> LDS row seg*8+(i>>3), LDS block i&7;
    // global block loaded = (i&7)^(i>>3)  => LDS blk b holds glob blk b^(r&7)
    const int srow = lane >> 3;                          // 0..7
    const int scol = ((lane & 7) ^ srow) << 3;           // swizzled, x8 ushorts

    const ushort_t* aBase = featb + (size_t)m0 * 1024;
    const ushort_t* bBase = w1t  + (size_t)n0 * 1024;

    // Precompute swizzled LDS read offsets (loop-invariant over kt).
    int aoff[4][2], boff[4][2];
#pragma unroll
    for (int t = 0; t < 4; t++) {
        const int ra = wr + t * 16 + l15;    // 0..255
        const int rb = wc + t * 16 + l15;    // 0..127
        aoff[t][0] = ra * 64 + (((q    ) ^ (ra & 7)) << 3);
        aoff[t][1] = ra * 64 + (((q + 4) ^ (ra & 7)) << 3);
        boff[t][0] = rb * 64 + (((q    ) ^ (rb & 7)) << 3);
        boff[t][1] = rb * 64 + (((q + 4) ^ (rb & 7)) << 3);
    }

    for (int kt = 0; kt < 1024; kt += 64) {
        // A: 32 segs of 8 rows; 4 per wave. B: 16 segs; 2 per wave.
#pragma unroll
        for (int p = 0; p < 4; p++) {
            const int seg = wave * 4 + p;            // 0..31
            const int row = seg * 8 + srow;          // 0..255
            gload_lds16(aBase + (size_t)row * 1024 + kt + scol, As + seg * 512);
        }
#pragma unroll
        for (int p = 0; p < 2; p++) {
            const int seg = wave * 2 + p;            // 0..15
            const int row = seg * 8 + srow;          // 0..127
            gload_lds16(bBase + (size_t)row * 1024 + kt + scol, Bs + seg * 512);
        }
        __syncthreads();
#pragma unroll
        for (int h = 0; h < 2; h++) {
            bf16x8 af[4], bfr[4];
#pragma unroll
            for (int t = 0; t < 4; t++) af[t]  = *(const bf16x8*)&As[aoff[t][h]];
#pragma unroll
            for (int t = 0; t < 4; t++) bfr[t] = *(const bf16x8*)&Bs[boff[t][h]];
#pragma unroll
            for (int tm = 0; tm < 4; tm++)
#pragma unroll
                for (int tn = 0; tn < 4; tn++)
                    acc[tm][tn] = __builtin_amdgcn_mfma_f32_16x16x32_bf16(
                        af[tm], bfr[tn], acc[tm][tn], 0, 0, 0);
        }
        __syncthreads();
    }

    // Epilogue: C/D layout col=lane&15, row=quad*4+reg (measured m89/m91).
    // sum_col tanh(x)*v = sum(v) - 2*sum(v/(e^{2x}+1)); e^{2x}=2^(x*2/ln2).
    float vv[4], cbk[4];
    float sum_vvw = 0.f;
#pragma unroll
    for (int tn = 0; tn < 4; tn++) {
        const int col = wc + tn * 16 + l15;
        vv[tn]  = vvw[col];
        cbk[tn] = LOG2E2 * cbias[col];
        sum_vvw += vv[tn];
    }
    // Waves with same wr but different wc cover different column halves ->
    // separate partial slice per column half (slot), rows unique per slot.
    const int slot = nt * 2 + (wave & 1);
#pragma unroll
    for (int tm = 0; tm < 4; tm++) {
#pragma unroll
        for (int r = 0; r < 4; r++) {
            const int row = wr + tm * 16 + q * 4 + r;   // 0..255
            float s2 = 0.f;
#pragma unroll
            for (int tn = 0; tn < 4; tn++) {
                const float arg = fmaf(LOG2E2, acc[tm][tn][r], cbk[tn]);
                const float e   = __builtin_amdgcn_exp2f(arg);
                s2 = fmaf(__builtin_amdgcn_rcpf(1.0f + e), vv[tn], s2);
            }
            float s = fmaf(-2.0f, s2, sum_vvw);
            s += __shfl_xor(s, 1);
            s += __shfl_xor(s, 2);
            s += __shfl_xor(s, 4);
            s += __shfl_xor(s, 8);
            if (l15 == 0) part[slot * 65536 + m0 + row] = s;
        }
    }
}

// ---------------- softmax over L per b (sums 16 partials/row) ---------------
__global__ __launch_bounds__(256) void softmax_kernel(
    const float* __restrict__ part, float* __restrict__ alpha) {
    const int b = blockIdx.x;
    const int tid = threadIdx.x;
    __shared__ float red[256];
    float v[4];
    float mx = -1e30f;
#pragma unroll
    for (int i = 0; i < 4; i++) {
        const int m = b * 1024 + tid + i * 256;
        float s = 0.f;
#pragma unroll
        for (int nb = 0; nb < 16; nb++) s += part[nb * 65536 + m];
        v[i] = s;
        mx = fmaxf(mx, s);
    }
    red[tid] = mx; __syncthreads();
    for (int s = 128; s > 0; s >>= 1) {
        if (tid < s) red[tid] = fmaxf(red[tid], red[tid + s]);
        __syncthreads();
    }
    mx = red[0]; __syncthreads();
    float sum = 0.f;
#pragma unroll
    for (int i = 0; i < 4; i++) { v[i] = __expf(v[i] - mx); sum += v[i]; }
    red[tid] = sum; __syncthreads();
    for (int s = 128; s > 0; s >>= 1) {
        if (tid < s) red[tid] += red[tid + s];
        __syncthreads();
    }
    const float inv = 1.0f / red[0];
#pragma unroll
    for (int i = 0; i < 4; i++)
        alpha[b * 1024 + tid + i * 256] = v[i] * inv;
}

// ---------------- context = alpha^T @ featb (bf16 feat) ---------------------
__global__ __launch_bounds__(1024) void context_bf16_kernel(
    const float* __restrict__ alpha, const ushort_t* __restrict__ featb,
    float* __restrict__ ctx) {
    const int b  = blockIdx.y;
    const int el = threadIdx.x & 63;               // e4 lane
    const int lg = threadIdx.x >> 6;               // 0..15
    const int e  = blockIdx.x * 256 + el * 4;
    const ushort_t* fb = featb + ((size_t)b << 20) + e;
    const float* ab = alpha + b * 1024;
    floatx4 acc = {};
    const int l0 = lg * 64;
#pragma unroll 4
    for (int l = l0; l < l0 + 64; l++) {
        const float a = ab[l];
        const ushort4 u = *(const ushort4*)(fb + (size_t)l * 1024);
        acc[0] = fmaf(a, b2f(u.x), acc[0]);
        acc[1] = fmaf(a, b2f(u.y), acc[1]);
        acc[2] = fmaf(a, b2f(u.z), acc[2]);
        acc[3] = fmaf(a, b2f(u.w), acc[3]);
    }
    __shared__ floatx4 red[16 * 64];
    red[lg * 64 + el] = acc;
    __syncthreads();
#pragma unroll
    for (int s = 8; s > 0; s >>= 1) {
        if (lg < s) red[lg * 64 + el] += red[(lg + s) * 64 + el];
        __syncthreads();
    }
    if (lg == 0)
        *(floatx4*)(ctx + b * 1024 + e) = red[el];
}

// ---------------- context fp32 (fallback path only) -------------------------
__global__ __launch_bounds__(1024) void context_kernel(
    const float* __restrict__ alpha, const float* __restrict__ feat,
    float* __restrict__ ctx) {
    const int b  = blockIdx.y;
    const int el = threadIdx.x & 63;
    const int lg = threadIdx.x >> 6;
    const int e  = blockIdx.x * 256 + el * 4;
    const float* fb = feat + (size_t)b * 1024 * 1024;
    const float* ab = alpha + b * 1024;
    floatx4 acc = {};
    const int l0 = lg * 64;
#pragma unroll 4
    for (int l = l0; l < l0 + 64; l++) {
        const float a = ab[l];
        const floatx4 f = *(const floatx4*)(fb + (size_t)l * 1024 + e);
        acc += a * f;
    }
    __shared__ floatx4 red[16 * 64];
    red[lg * 64 + el] = acc;
    __syncthreads();
#pragma unroll
    for (int s = 8; s > 0; s >>= 1) {
        if (lg < s) red[lg * 64 + el] += red[(lg + s) * 64 + el];
        __syncthreads();
    }
    if (lg == 0)
        *(floatx4*)(ctx + b * 1024 + e) = red[el];
}

// ---------------- fallback GEMM (fp32 A staging, padded LDS, 128x128) -------
#define KP 72
__global__ __launch_bounds__(256) void gemm_scores_f32_kernel(
    const float* __restrict__ feat, const ushort_t* __restrict__ w1t,
    const float* __restrict__ ph, const float* __restrict__ vw,
    float* __restrict__ part) {
    __shared__ ushort_t As[128 * KP];
    __shared__ ushort_t Bs[128 * KP];
    __shared__ float cbias[128];
    __shared__ float vvw[128];
    const int tid = threadIdx.x;
    const int nt = blockIdx.x, n0 = nt * 128, m0 = blockIdx.y * 128;
    const int b = m0 >> 10;
    if (tid < 128) { cbias[tid] = ph[(b << 10) + n0 + tid]; vvw[tid] = vw[n0 + tid]; }
    const int wave = tid >> 6, lane = tid & 63;
    const int wr = (wave >> 1) * 64, wc = (wave & 1) * 64;
    const int q = lane >> 4, l15 = lane & 15;
    floatx4 acc[4][4] = {};
    const int arow = tid >> 4, acol = (tid & 15) * 4;
    const int brow = tid >> 3, bcol = (tid & 7) * 8;
    const float* aptr = feat + (size_t)m0 * 1024;
    const ushort_t* bptr = w1t + (size_t)n0 * 1024;
    for (int kt = 0; kt < 1024; kt += 64) {
#pragma unroll
        for (int p = 0; p < 8; p++) {
            int r = p * 16 + arow;
            const float4 f = *(const float4*)(aptr + (size_t)r * 1024 + kt + acol);
            *(u64*)&As[r * KP + acol] = pack4(f);
        }
#pragma unroll
        for (int p = 0; p < 4; p++) {
            int r = p * 32 + brow;
            *(uint4*)&Bs[r * KP + bcol] =
                *(const uint4*)(bptr + (size_t)r * 1024 + kt + bcol);
        }
        __syncthreads();
#pragma unroll
        for (int ks = 0; ks < 64; ks += 32) {
            bf16x8 af[4], bfr[4];
#pragma unroll
            for (int t = 0; t < 4; t++)
                af[t] = *(const bf16x8*)&As[(wr + t * 16 + l15) * KP + ks + q * 8];
#pragma unroll
            for (int t = 0; t < 4; t++)
                bfr[t] = *(const bf16x8*)&Bs[(wc + t * 16 + l15) * KP + ks + q * 8];
#pragma unroll
            for (int tm = 0; tm < 4; tm++)
#pragma unroll
                for (int tn = 0; tn < 4; tn++)
                    acc[tm][tn] = __builtin_amdgcn_mfma_f32_16x16x32_bf16(
                        af[tm], bfr[tn], acc[tm][tn], 0, 0, 0);
        }
        __syncthreads();
    }
    const int slot = nt * 2 + (wave & 1);
#pragma unroll
    for (int tm = 0; tm < 4; tm++) {
#pragma unroll
        for (int r = 0; r < 4; r++) {
            const int row = wr + tm * 16 + q * 4 + r;
            float s = 0.f;
#pragma unroll
            for (int tn = 0; tn < 4; tn++) {
                const int col = wc + tn * 16 + l15;
                s += fast_tanh(acc[tm][tn][r] + cbias[col]) * vvw[col];
            }
            s += __shfl_xor(s, 1);
            s += __shfl_xor(s, 2);
            s += __shfl_xor(s, 4);
            s += __shfl_xor(s, 8);
            if (l15 == 0) part[slot * 65536 + m0 + row] = s;
        }
    }
}

// ---------------- launcher --------------------------------------------------
extern "C" void kernel_launch(void* const* d_in, const int* in_sizes, int n_in,
                              void* d_out, int out_size, void* d_ws, size_t ws_size,
                              hipStream_t stream) {
    const float* feat = (const float*)d_in[0];   // [64,1024,1024]
    const float* hid  = (const float*)d_in[1];   // [64,1024]
    const float* w1w  = (const float*)d_in[2];   // [1024,1024]
    const float* w1b  = (const float*)d_in[3];   // [1024]
    const float* w2w  = (const float*)d_in[4];   // [1024,1024]
    const float* w2b  = (const float*)d_in[5];   // [1024]
    const float* vw   = (const float*)d_in[6];   // [1024]
    // d_in[7] = V_b: cancels in softmax -> unused

    const size_t FEATB_BYTES = (size_t)64 * 1024 * 1024 * 2;  // 128 MB
    const size_t W1T_BYTES   = (size_t)1024 * 1024 * 2;       // 2 MB
    const size_t PH_BYTES    = (size_t)64 * 1024 * 4;         // 256 KB
    const size_t PART_BYTES  = (size_t)16 * 65536 * 4;        // 4 MB
    const bool   big_ws = ws_size >= FEATB_BYTES + W1T_BYTES + PH_BYTES + PART_BYTES;
    if (!big_ws && ws_size < W1T_BYTES + PH_BYTES + PART_BYTES) return;

    char* ws = (char*)d_ws;
    ushort_t* featb = (ushort_t*)ws;
    size_t off = big_ws ? FEATB_BYTES : 0;
    ushort_t* w1t  = (ushort_t*)(ws + off);
    float* ph      = (float*)(ws + off + W1T_BYTES);
    float* part    = (float*)(ws + off + W1T_BYTES + PH_BYTES);

    float* alpha = (float*)d_out;           // [64,1024]
    float* ctx   = alpha + 64 * 1024;       // [64,1024]

    transpose_w1_kernel<<<dim3(16, 16), 256, 0, stream>>>(w1w, w1t);
    projh_kernel<<<dim3(16, 64), 256, 0, stream>>>(hid, w2w, w2b, w1b, ph);
    if (big_ws) {
        convert_feat_kernel<<<32768, 256, 0, stream>>>(feat, featb);
        gemm_scores_bf16_kernel<<<dim3(8, 256), 512, 0, stream>>>(
            featb, w1t, ph, vw, part);
        softmax_kernel<<<64, 256, 0, stream>>>(part, alpha);
        context_bf16_kernel<<<dim3(4, 64), 1024, 0, stream>>>(alpha, featb, ctx);
    } else {
        gemm_scores_f32_kernel<<<dim3(8, 512), 256, 0, stream>>>(
            feat, w1t, ph, vw, part);
        softmax_kernel<<<64, 256, 0, stream>>>(part, alpha);
        context_kernel<<<dim3(4, 64), 1024, 0, stream>>>(alpha, feat, ctx);
    }
}